// Round 1
// 418.024 us; speedup vs baseline: 1.0067x; 1.0067x over previous
//
#include <hip/hip_runtime.h>
#include <stdint.h>

// W8A8B32O32 Linear: y[m][n] = sum_k x[m][k]*w[n][k] + bias[n]
// M=8192, N=4096, K=4096. Inputs arrive as int32 (one int per logical int8
// element); pack to int8 in d_ws, then run the i8 MFMA GEMM.
#define M_TOT 8192
#define N_TOT 4096
#define K_TOT 4096

typedef int v4i  __attribute__((ext_vector_type(4)));
typedef int v16i __attribute__((ext_vector_type(16)));

__device__ __forceinline__ void gload_lds16(const void* g, void* l) {
    __builtin_amdgcn_global_load_lds(
        (const __attribute__((address_space(1))) unsigned int*)g,
        (__attribute__((address_space(3))) unsigned int*)l,
        16, 0, 0);
}

// s_waitcnt vmcnt(0) only: gfx9 simm16 = vmcnt[3:0]|[15:14]=0,
// expcnt[6:4]=7, lgkmcnt[11:8]=15 -> 0x0f70.
#define WAIT_VMCNT0() __builtin_amdgcn_s_waitcnt(0x0f70)

// ---- pack int32 -> int8, coalesced (16B load / 4B store per lane), 4x ----
__global__ __launch_bounds__(256) void pack_i32_to_i8(
        const int4* __restrict__ src, int* __restrict__ dst, int n4) {
    int idx = blockIdx.x * 1024 + threadIdx.x;
#pragma unroll
    for (int u = 0; u < 4; ++u, idx += 256) {
        const int4 a = src[idx];
        dst[idx] = (a.x & 255) | ((a.y & 255) << 8) |
                   ((a.z & 255) << 16) | (a.w << 24);
    }
}

// ---- GEMM: 256 threads = 4 waves computing a 256x256 tile -----------------
// Why 256x256: the 128x128/1-wave version was L2-BW bound — AI = 64 MACs per
// staged byte needs ~34 TB/s L2 traffic to feed the 4.4 POPS i8 pipe, which
// IS the L2 ceiling (MfmaUtil measured 42%). 256x256 doubles AI to 128
// MACs/byte (per-CU staging halves: 32 KB per 1170-cyc MFMA period).
// Each wave owns one 128x128 quadrant; its inner loop (16 ds_read_b128 +
// 32 MFMAs + XOR chunk swizzle) is identical to the proven 128x128 kernel;
// only staging shrinks to 8 DMA issues/wave.
//
// Pipeline per K-iter: [own vmcnt(0)] -> [s_barrier: all 4 waves' DMAs for
// cur landed] -> [ds_read 16 frags of cur] -> [issue 8 DMAs for nxt] ->
// [32 MFMAs ~1170 cyc cover the DMAs]. Barrier safety: the barrier at iter
// kt separates all of iter kt-1's ds_reads (consumed by kt-1's MFMAs via
// data dependence) from iter kt's DMA issues into that same buffer. The
// explicit vmcnt wait is REQUIRED: compiler alias analysis does not connect
// global_load_lds's LDS write to the ds_reads.
// XOR chunk swizzle: stored_chunk = logical_chunk ^ ((row>>1)&3); staging
// stays linear-in-load-order (global_load_lds needs wave-uniform LDS base).
__global__ __launch_bounds__(256, 1) void i8gemm_bias(
        const signed char* __restrict__ x,
        const signed char* __restrict__ w,
        const int* __restrict__ bias,
        int* __restrict__ out) {
    __shared__ __align__(16) signed char la[2][256 * 64];
    __shared__ __align__(16) signed char lb[2][256 * 64];

    const int tid  = threadIdx.x;
    const int lane = tid & 63;           // 0..63
    const int wv   = tid >> 6;           // wave 0..3
    const int l31  = lane & 31;
    const int kh   = lane >> 5;          // K-half this lane supplies to MFMA
    const int wr   = wv >> 1;            // wave's quadrant row (0..1)
    const int wc   = wv & 1;             // wave's quadrant col (0..1)

    // XCD-aware bijective swizzle (512 blocks, 512%8==0): XCD k gets a
    // contiguous swz-range -> 4 A-panels x all 16 B-panels per XCD. Per-K-step
    // working set ~320 KB << 4 MB L2; A fetched once chip-wide.
    const int flat = blockIdx.y * gridDim.x + blockIdx.x;   // 0..511
    const int swz  = (flat & 7) * 64 + (flat >> 3);
    const int bn0  = (swz & 15) * 256;
    const int bm0  = (swz >> 4) * 256;

    // Fused bias: C/D col = lane&31 -> bias is lane-constant per fragment.
    int bv[4];
#pragma unroll
    for (int j = 0; j < 4; ++j) bv[j] = bias[bn0 + wc * 128 + j * 32 + l31];
    v16i acc[4][4];
#pragma unroll
    for (int i = 0; i < 4; ++i)
#pragma unroll
        for (int j = 0; j < 4; ++j)
#pragma unroll
            for (int r = 0; r < 16; ++r) acc[i][j][r] = bv[j];

    // Staging: wave wv covers rows [wv*64, wv*64+64) of both A and B tiles:
    // 4 issues x (64 lanes x 16 B) each. Issue i covers rows i*16+(lane>>2);
    // stored chunk = lane&3; fetched chunk = (lane&3) ^ ((row>>1)&3)
    // = (lane&3) ^ ((lane>>3)&3)  (wv*64 and i*16 are 0 mod 4 after >>1).
    const int fc = (lane & 3) ^ ((lane >> 3) & 3);
    const signed char* pa = x + (long)(bm0 + wv * 64 + (lane >> 2)) * K_TOT + fc * 16;
    const signed char* pb = w + (long)(bn0 + wv * 64 + (lane >> 2)) * K_TOT + fc * 16;
    const int lbase = wv * 64 * 64;      // byte offset of this wave's rows

    // Fragment reads: row = wr*128 + i*32 + l31 -> swizzle = (l31>>1)&3,
    // invariant (wr*128 and i*32 are 0 mod 4 after >>1).
    const int swr = (l31 >> 1) & 3;

    // Prologue: all 4 waves stage kt=0 into buffer 0.
#pragma unroll
    for (int i = 0; i < 4; ++i) {
        gload_lds16(pa + (long)i * 16 * K_TOT, &la[0][lbase + i * 1024]);
        gload_lds16(pb + (long)i * 16 * K_TOT, &lb[0][lbase + i * 1024]);
    }

    for (int kt = 0; kt < K_TOT / 64; ++kt) {
        const int cur = kt & 1;
        const signed char* lac = la[cur];
        const signed char* lbc = lb[cur];

        // 0) Own DMAs for cur landed; barrier -> everyone's landed.
        WAIT_VMCNT0();
        __builtin_amdgcn_s_barrier();
        __builtin_amdgcn_sched_barrier(0);

        // 1) All fragment reads of the current buffer.
        // A/B operand 32x32x32_i8: m(n)=lane&31, k=(lane>>5)*16+byte ->
        // lane reads 16 contiguous bytes at logical chunk kk*2 + kh.
        v4i af[2][4], bf[2][4];
#pragma unroll
        for (int kk = 0; kk < 2; ++kk) {
            const int cs = ((kk * 2 + kh) ^ swr) * 16;
#pragma unroll
            for (int i = 0; i < 4; ++i) {
                af[kk][i] = *(const v4i*)(lac + (wr * 128 + i * 32 + l31) * 64 + cs);
                bf[kk][i] = *(const v4i*)(lbc + (wc * 128 + i * 32 + l31) * 64 + cs);
            }
        }
        __builtin_amdgcn_sched_barrier(0);

        // 2) Prefetch next K-tile into the other buffer (fire-and-forget).
        if (kt + 1 < K_TOT / 64) {
            const long k0 = (long)(kt + 1) * 64;
            signed char* lan = la[cur ^ 1] + lbase;
            signed char* lbn = lb[cur ^ 1] + lbase;
#pragma unroll
            for (int i = 0; i < 4; ++i) {
                gload_lds16(pa + k0 + (long)i * 16 * K_TOT, lan + i * 1024);
                gload_lds16(pb + k0 + (long)i * 16 * K_TOT, lbn + i * 1024);
            }
        }
        __builtin_amdgcn_sched_barrier(0);

        // 3) Compute: 32 MFMAs (~1170 cyc of matrix pipe) cover the prefetch.
#pragma unroll
        for (int kk = 0; kk < 2; ++kk)
#pragma unroll
            for (int i = 0; i < 4; ++i)
#pragma unroll
                for (int j = 0; j < 4; ++j)
                    acc[i][j] = __builtin_amdgcn_mfma_i32_32x32x32_i8(
                        af[kk][i], bf[kk][j], acc[i][j], 0, 0, 0);
    }

    // Epilogue: C/D layout col=lane&31, row=(reg&3)+8*(reg>>2)+4*(lane>>5).
#pragma unroll
    for (int i = 0; i < 4; ++i) {
        const int mbase = bm0 + wr * 128 + i * 32 + 4 * kh;
#pragma unroll
        for (int j = 0; j < 4; ++j) {
            const int n = bn0 + wc * 128 + j * 32 + l31;
#pragma unroll
            for (int r = 0; r < 16; ++r) {
                const int m = mbase + (r & 3) + 8 * (r >> 2);
                out[(long)m * N_TOT + n] = acc[i][j][r];
            }
        }
    }
}

extern "C" void kernel_launch(void* const* d_in, const int* in_sizes, int n_in,
                              void* d_out, int out_size, void* d_ws, size_t ws_size,
                              hipStream_t stream) {
    const int* x32  = (const int*)d_in[0];  // [8192,4096] logical i8 as i32
    const int* w32  = (const int*)d_in[1];  // [4096,4096] logical i8 as i32
    const int* bias = (const int*)d_in[2];  // [4096] i32
    int*       out  = (int*)d_out;          // [8192,4096] i32

    signed char* xp = (signed char*)d_ws;
    signed char* wp = (signed char*)d_ws + (size_t)M_TOT * K_TOT;

    const int n4x = (M_TOT * K_TOT) / 4;  // 8388608 (divisible by 1024)
    const int n4w = (N_TOT * K_TOT) / 4;  // 4194304 (divisible by 1024)
    pack_i32_to_i8<<<n4x / 1024, 256, 0, stream>>>((const int4*)x32, (int*)xp, n4x);
    pack_i32_to_i8<<<n4w / 1024, 256, 0, stream>>>((const int4*)w32, (int*)wp, n4w);

    dim3 grid(N_TOT / 256, M_TOT / 256);  // (16, 32)
    i8gemm_bias<<<grid, 256, 0, stream>>>(xp, wp, bias, out);
}

// Round 2
// 404.579 us; speedup vs baseline: 1.0402x; 1.0332x over previous
//
#include <hip/hip_runtime.h>
#include <stdint.h>

// W8A8B32O32 Linear: y[m][n] = sum_k x[m][k]*w[n][k] + bias[n]
// M=8192, N=4096, K=4096. Inputs arrive as int32 (one int per logical int8
// element); pack to int8 in d_ws, then run the i8 MFMA GEMM.
#define M_TOT 8192
#define N_TOT 4096
#define K_TOT 4096

typedef int v4i  __attribute__((ext_vector_type(4)));
typedef int v16i __attribute__((ext_vector_type(16)));

__device__ __forceinline__ void gload_lds16(const void* g, void* l) {
    __builtin_amdgcn_global_load_lds(
        (const __attribute__((address_space(1))) unsigned int*)g,
        (__attribute__((address_space(3))) unsigned int*)l,
        16, 0, 0);
}

// s_waitcnt with lgkmcnt=15, expcnt=7 (ignored), vmcnt=N:
// gfx9 simm16 = vmcnt[3:0] | expcnt[6:4] | lgkmcnt[11:8] | vmcnt[5:4]@[15:14].
#define WAIT_VMCNT0() __builtin_amdgcn_s_waitcnt(0x0f70)
#define WAIT_VMCNT8() __builtin_amdgcn_s_waitcnt(0x0f78)

// ---- pack int32 -> int8, coalesced (16B load / 4B store per lane), 4x ----
__global__ __launch_bounds__(256) void pack_i32_to_i8(
        const int4* __restrict__ src, int* __restrict__ dst, int n4) {
    int idx = blockIdx.x * 1024 + threadIdx.x;
#pragma unroll
    for (int u = 0; u < 4; ++u, idx += 256) {
        const int4 a = src[idx];
        dst[idx] = (a.x & 255) | ((a.y & 255) << 8) |
                   ((a.z & 255) << 16) | (a.w << 24);
    }
}

// ---- GEMM: 256 threads = 4 waves computing a 256x256 tile -----------------
// R1 post-mortem: at 1 wave/SIMD (428 unified regs) there is NO TLP; the
// vmcnt(0) wait exposed ~1600 cyc/iter of DMA completion latency (per-iter
// wall 3120 cyc vs 1170 cyc MFMA -> MfmaUtil 35%). Staging BW is NOT the
// limit (6.4 TB/s L2->LDS vs 34.5 ceiling).
// Fix: prefetch distance 2. Triple-buffered LDS (3 x 32 KB), issue tile
// kt+2 right after the barrier, wait vmcnt(8) -- the 8 DMAs/wave of tile
// kt+1 stay in flight across the wait (T4 counted-vmcnt). Each tile gets
// ~2 full iterations from issue to consumption.
//
// Per K-iter: [vmcnt(8): tile kt landed (in-order decrement)] ->
// [s_barrier: ALL waves' tile-kt DMAs landed] -> [issue 8 DMAs tile kt+2]
// -> [16 ds_read_b128 of tile kt] -> [32 MFMAs].
// Buffer-reuse safety: tile kt+2's buffer was last ds_read at iter kt-1;
// every wave's reads complete before it reaches the barrier at iter kt
// (MFMA data dependence drains lgkm), and the issue is after that barrier.
// The explicit vmcnt wait is REQUIRED: compiler alias analysis does not
// connect global_load_lds's LDS write to the ds_reads.
// XOR chunk swizzle: stored_chunk = logical_chunk ^ ((row>>1)&3); staging
// stays linear-in-load-order (global_load_lds needs wave-uniform LDS base).
__global__ __launch_bounds__(256, 1) void i8gemm_bias(
        const signed char* __restrict__ x,
        const signed char* __restrict__ w,
        const int* __restrict__ bias,
        int* __restrict__ out) {
    __shared__ __align__(16) signed char la[3][256 * 64];
    __shared__ __align__(16) signed char lb[3][256 * 64];

    const int tid  = threadIdx.x;
    const int lane = tid & 63;           // 0..63
    const int wv   = tid >> 6;           // wave 0..3
    const int l31  = lane & 31;
    const int kh   = lane >> 5;          // K-half this lane supplies to MFMA
    const int wr   = wv >> 1;            // wave's quadrant row (0..1)
    const int wc   = wv & 1;             // wave's quadrant col (0..1)

    // XCD-aware bijective swizzle (512 blocks, 512%8==0): XCD k gets a
    // contiguous swz-range -> 4 A-panels x all 16 B-panels per XCD.
    const int flat = blockIdx.y * gridDim.x + blockIdx.x;   // 0..511
    const int swz  = (flat & 7) * 64 + (flat >> 3);
    const int bn0  = (swz & 15) * 256;
    const int bm0  = (swz >> 4) * 256;

    // Fused bias: C/D col = lane&31 -> bias is lane-constant per fragment.
    int bv[4];
#pragma unroll
    for (int j = 0; j < 4; ++j) bv[j] = bias[bn0 + wc * 128 + j * 32 + l31];
    v16i acc[4][4];
#pragma unroll
    for (int i = 0; i < 4; ++i)
#pragma unroll
        for (int j = 0; j < 4; ++j)
#pragma unroll
            for (int r = 0; r < 16; ++r) acc[i][j][r] = bv[j];

    // Staging: wave wv covers rows [wv*64, wv*64+64) of both A and B tiles:
    // 4 issues x (64 lanes x 16 B) each. Issue i covers rows i*16+(lane>>2);
    // stored chunk = lane&3; fetched chunk = (lane&3) ^ ((row>>1)&3)
    // = (lane&3) ^ ((lane>>3)&3)  (wv*64 and i*16 are 0 mod 4 after >>1).
    const int fc = (lane & 3) ^ ((lane >> 3) & 3);
    const signed char* pa = x + (long)(bm0 + wv * 64 + (lane >> 2)) * K_TOT + fc * 16;
    const signed char* pb = w + (long)(bn0 + wv * 64 + (lane >> 2)) * K_TOT + fc * 16;
    const int lbase = wv * 64 * 64;      // byte offset of this wave's rows

    // Fragment reads: row = wr*128 + i*32 + l31 -> swizzle = (l31>>1)&3,
    // invariant (wr*128 and i*32 are 0 mod 4 after >>1).
    const int swr = (l31 >> 1) & 3;

    // Rotating buffer pointers: A0/B0 = tile kt, A1/B1 = kt+1, A2/B2 = kt+2.
    signed char* A0 = &la[0][0]; signed char* A1 = &la[1][0]; signed char* A2 = &la[2][0];
    signed char* B0 = &lb[0][0]; signed char* B1 = &lb[1][0]; signed char* B2 = &lb[2][0];

    // Prologue: stage tile 0 -> buf0 (8 DMAs/wave), tile 1 -> buf1 (8 more).
    // vmcnt decrements in issue order, so group strictly per tile.
#pragma unroll
    for (int i = 0; i < 4; ++i) {
        gload_lds16(pa + (long)i * 16 * K_TOT, A0 + lbase + i * 1024);
        gload_lds16(pb + (long)i * 16 * K_TOT, B0 + lbase + i * 1024);
    }
#pragma unroll
    for (int i = 0; i < 4; ++i) {
        gload_lds16(pa + 64 + (long)i * 16 * K_TOT, A1 + lbase + i * 1024);
        gload_lds16(pb + 64 + (long)i * 16 * K_TOT, B1 + lbase + i * 1024);
    }

    const int NT = K_TOT / 64;           // 64 K-tiles
    for (int kt = 0; kt < NT; ++kt) {
        // 0) Oldest 8 DMAs (tile kt) landed; keep tile kt+1's 8 in flight.
        if (kt == NT - 1) { WAIT_VMCNT0(); } else { WAIT_VMCNT8(); }
        __builtin_amdgcn_s_barrier();
        __builtin_amdgcn_sched_barrier(0);

        // 1) Issue prefetch of tile kt+2 ASAP (fire-and-forget).
        if (kt + 2 < NT) {
            const long k0 = (long)(kt + 2) * 64;
#pragma unroll
            for (int i = 0; i < 4; ++i) {
                gload_lds16(pa + k0 + (long)i * 16 * K_TOT, A2 + lbase + i * 1024);
                gload_lds16(pb + k0 + (long)i * 16 * K_TOT, B2 + lbase + i * 1024);
            }
        }
        __builtin_amdgcn_sched_barrier(0);

        // 2) All fragment reads of the current buffer.
        // A/B operand 32x32x32_i8: m(n)=lane&31, k=(lane>>5)*16+byte ->
        // lane reads 16 contiguous bytes at logical chunk kk*2 + kh.
        v4i af[2][4], bf[2][4];
#pragma unroll
        for (int kk = 0; kk < 2; ++kk) {
            const int cs = ((kk * 2 + kh) ^ swr) * 16;
#pragma unroll
            for (int i = 0; i < 4; ++i) {
                af[kk][i] = *(const v4i*)(A0 + (wr * 128 + i * 32 + l31) * 64 + cs);
                bf[kk][i] = *(const v4i*)(B0 + (wc * 128 + i * 32 + l31) * 64 + cs);
            }
        }
        __builtin_amdgcn_sched_barrier(0);

        // 3) Compute: 32 MFMAs (~1170 cyc matrix pipe) cover the prefetch.
#pragma unroll
        for (int kk = 0; kk < 2; ++kk)
#pragma unroll
            for (int i = 0; i < 4; ++i)
#pragma unroll
                for (int j = 0; j < 4; ++j)
                    acc[i][j] = __builtin_amdgcn_mfma_i32_32x32x32_i8(
                        af[kk][i], bf[kk][j], acc[i][j], 0, 0, 0);

        // 4) Rotate buffers (register pointer swap, no dynamic indexing).
        signed char* t;
        t = A0; A0 = A1; A1 = A2; A2 = t;
        t = B0; B0 = B1; B1 = B2; B2 = t;
    }

    // Epilogue: C/D layout col=lane&31, row=(reg&3)+8*(reg>>2)+4*(lane>>5).
#pragma unroll
    for (int i = 0; i < 4; ++i) {
        const int mbase = bm0 + wr * 128 + i * 32 + 4 * kh;
#pragma unroll
        for (int j = 0; j < 4; ++j) {
            const int n = bn0 + wc * 128 + j * 32 + l31;
#pragma unroll
            for (int r = 0; r < 16; ++r) {
                const int m = mbase + (r & 3) + 8 * (r >> 2);
                out[(long)m * N_TOT + n] = acc[i][j][r];
            }
        }
    }
}

extern "C" void kernel_launch(void* const* d_in, const int* in_sizes, int n_in,
                              void* d_out, int out_size, void* d_ws, size_t ws_size,
                              hipStream_t stream) {
    const int* x32  = (const int*)d_in[0];  // [8192,4096] logical i8 as i32
    const int* w32  = (const int*)d_in[1];  // [4096,4096] logical i8 as i32
    const int* bias = (const int*)d_in[2];  // [4096] i32
    int*       out  = (int*)d_out;          // [8192,4096] i32

    signed char* xp = (signed char*)d_ws;
    signed char* wp = (signed char*)d_ws + (size_t)M_TOT * K_TOT;

    const int n4x = (M_TOT * K_TOT) / 4;  // 8388608 (divisible by 1024)
    const int n4w = (N_TOT * K_TOT) / 4;  // 4194304 (divisible by 1024)
    pack_i32_to_i8<<<n4x / 1024, 256, 0, stream>>>((const int4*)x32, (int*)xp, n4x);
    pack_i32_to_i8<<<n4w / 1024, 256, 0, stream>>>((const int4*)w32, (int*)wp, n4w);

    dim3 grid(N_TOT / 256, M_TOT / 256);  // (16, 32)
    i8gemm_bias<<<grid, 256, 0, stream>>>(xp, wp, bias, out);
}

// Round 3
// 403.575 us; speedup vs baseline: 1.0428x; 1.0025x over previous
//
#include <hip/hip_runtime.h>
#include <stdint.h>

// W8A8B32O32 Linear: y[m][n] = sum_k x[m][k]*w[n][k] + bias[n]
// M=8192, N=4096, K=4096. Inputs arrive as int32 (one int per logical int8
// element); pack to int8 in d_ws, then run the i8 MFMA GEMM.
#define M_TOT 8192
#define N_TOT 4096
#define K_TOT 4096

typedef int v4i  __attribute__((ext_vector_type(4)));
typedef int v16i __attribute__((ext_vector_type(16)));

__device__ __forceinline__ void gload_lds16(const void* g, void* l) {
    __builtin_amdgcn_global_load_lds(
        (const __attribute__((address_space(1))) unsigned int*)g,
        (__attribute__((address_space(3))) unsigned int*)l,
        16, 0, 0);
}

// gfx9 s_waitcnt simm16: vmcnt[3:0]@[3:0], expcnt@[6:4], lgkmcnt@[11:8],
// vmcnt[5:4]@[15:14].
#define WAIT_V8_L0() __builtin_amdgcn_s_waitcnt(0x0078)  // vmcnt(8) lgkmcnt(0)
#define WAIT_V0_L0() __builtin_amdgcn_s_waitcnt(0x0070)  // vmcnt(0) lgkmcnt(0)
#define WAIT_V8()    __builtin_amdgcn_s_waitcnt(0x0f78)  // vmcnt(8), lgkm free
#define SBAR()       __builtin_amdgcn_s_barrier()
#define SFENCE()     __builtin_amdgcn_sched_barrier(0)

// ---- pack int32 -> int8, coalesced (16B load / 4B store per lane), 4x ----
__global__ __launch_bounds__(256) void pack_i32_to_i8(
        const int4* __restrict__ src, int* __restrict__ dst, int n4) {
    int idx = blockIdx.x * 1024 + threadIdx.x;
#pragma unroll
    for (int u = 0; u < 4; ++u, idx += 256) {
        const int4 a = src[idx];
        dst[idx] = (a.x & 255) | ((a.y & 255) << 8) |
                   ((a.z & 255) << 16) | (a.w << 24);
    }
}

// ---- GEMM: 256 threads = 4 waves computing a 256x256 tile -----------------
// R2 post-mortem: depth-2 prefetch was NEUTRAL (vmcnt already satisfied) ->
// the stall is NOT DMA latency. It is the SERIAL ds_read phase: the LDS pipe
// is per-CU shared (64 wave-reads x 1KB + 32KB DMA writes per CU-iter =
// ~750-1100 cyc at 85-128 B/cyc), and the old [reads | fence | MFMAs]
// structure made it ADDITIVE with the 1170-cyc MFMA block (35% MfmaUtil).
//
// Fix (T3, 2-phase): split the K-tile into kk-halves and hide each read
// batch under the OTHER half's 16 MFMAs (585 cyc >> ~300 cyc contended
// reads). Per iter:
//   1) ds_read kk=1 of tile kt            (hidden under step 3)
//   2) issue 8 DMAs tile kt+2             (fire-and-forget)
//   3) MFMA kk=0 (16)
//   4) s_waitcnt vmcnt(8) lgkmcnt(0)      (tile kt+1 landed; MY reads retired)
//   5) s_barrier                          (ALL waves: kt+1 landed, reads retired)
//   6) ds_read kk=0 of tile kt+1          (hidden under step 7)
//   7) MFMA kk=1 (16)
// Cross-wave buffer-reuse proof: DMA at iter kt step 2 targets the buffer
// last read at iter kt-1 (steps 1/6); iter kt-1's step-4 lgkmcnt(0) retires
// every wave's reads BEFORE its step-5 barrier, and step 2 is after that
// barrier. Reading tile kt+1 at step 6 is safe: each wave's step-4 vmcnt
// (its own kt+1 DMAs) precedes the same barrier. vmcnt counts per tile:
// after step 2 there are 16 outstanding (kt+1, kt+2); vmcnt(8) = kt+1 done.
// The explicit waits are REQUIRED for the cross-wave cases: compiler alias
// analysis does not connect global_load_lds's LDS write to the ds_reads.
// XOR chunk swizzle: stored_chunk = logical_chunk ^ ((row>>1)&3); staging
// stays linear-in-load-order (global_load_lds needs wave-uniform LDS base).
__global__ __launch_bounds__(256, 1) void i8gemm_bias(
        const signed char* __restrict__ x,
        const signed char* __restrict__ w,
        const int* __restrict__ bias,
        int* __restrict__ out) {
    __shared__ __align__(16) signed char la[3][256 * 64];
    __shared__ __align__(16) signed char lb[3][256 * 64];

    const int tid  = threadIdx.x;
    const int lane = tid & 63;           // 0..63
    const int wv   = tid >> 6;           // wave 0..3
    const int l31  = lane & 31;
    const int kh   = lane >> 5;          // K-half this lane supplies to MFMA
    const int wr   = wv >> 1;            // wave's quadrant row (0..1)
    const int wc   = wv & 1;             // wave's quadrant col (0..1)

    // XCD-aware bijective swizzle (512 blocks, 512%8==0): XCD k gets a
    // contiguous swz-range -> 4 A-panels x all 16 B-panels per XCD.
    const int flat = blockIdx.y * gridDim.x + blockIdx.x;   // 0..511
    const int swz  = (flat & 7) * 64 + (flat >> 3);
    const int bn0  = (swz & 15) * 256;
    const int bm0  = (swz >> 4) * 256;

    // Fused bias: C/D col = lane&31 -> bias is lane-constant per fragment.
    int bv[4];
#pragma unroll
    for (int j = 0; j < 4; ++j) bv[j] = bias[bn0 + wc * 128 + j * 32 + l31];
    v16i acc[4][4];
#pragma unroll
    for (int i = 0; i < 4; ++i)
#pragma unroll
        for (int j = 0; j < 4; ++j)
#pragma unroll
            for (int r = 0; r < 16; ++r) acc[i][j][r] = bv[j];

    // Staging: wave wv covers rows [wv*64, wv*64+64) of both A and B tiles:
    // 4 issues x (64 lanes x 16 B) each. Issue i covers rows i*16+(lane>>2);
    // stored chunk = lane&3; fetched chunk = (lane&3) ^ ((row>>1)&3)
    // = (lane&3) ^ ((lane>>3)&3)  (wv*64 and i*16 are 0 mod 4 after >>1).
    const int fc = (lane & 3) ^ ((lane >> 3) & 3);
    const signed char* pa = x + (long)(bm0 + wv * 64 + (lane >> 2)) * K_TOT + fc * 16;
    const signed char* pb = w + (long)(bn0 + wv * 64 + (lane >> 2)) * K_TOT + fc * 16;
    const int lbase = wv * 64 * 64;      // byte offset of this wave's rows

    // Fragment reads: row = {wr,wc}*128 + i*32 + l31 -> swizzle = (l31>>1)&3.
    // Logical chunk kk*2+kh at stored position (kk*2+kh)^swr.
    const int swr  = (l31 >> 1) & 3;
    const int aoff = (wr * 128 + l31) * 64;
    const int boff = (wc * 128 + l31) * 64;
    const int cs0  = ((kh    ) ^ swr) * 16;   // kk=0 chunk byte offset
    const int cs1  = ((2 + kh) ^ swr) * 16;   // kk=1 chunk byte offset

    // Rotating buffer pointers: A0/B0 = tile kt, A1/B1 = kt+1, A2/B2 = kt+2.
    signed char* A0 = &la[0][0]; signed char* A1 = &la[1][0]; signed char* A2 = &la[2][0];
    signed char* B0 = &lb[0][0]; signed char* B1 = &lb[1][0]; signed char* B2 = &lb[2][0];

    // Prologue: stage tile 0 -> buf0, tile 1 -> buf1 (grouped per tile:
    // vmcnt decrements in issue order).
#pragma unroll
    for (int i = 0; i < 4; ++i) {
        gload_lds16(pa + (long)i * 16 * K_TOT, A0 + lbase + i * 1024);
        gload_lds16(pb + (long)i * 16 * K_TOT, B0 + lbase + i * 1024);
    }
#pragma unroll
    for (int i = 0; i < 4; ++i) {
        gload_lds16(pa + 64 + (long)i * 16 * K_TOT, A1 + lbase + i * 1024);
        gload_lds16(pb + 64 + (long)i * 16 * K_TOT, B1 + lbase + i * 1024);
    }
    WAIT_V8();                 // tile 0 landed (tile 1's 8 stay in flight)
    SBAR();
    SFENCE();

    // Preload kk=0 fragments of tile 0.
    v4i a0[4], b0[4], a1[4], b1[4];
#pragma unroll
    for (int i = 0; i < 4; ++i) {
        a0[i] = *(const v4i*)(A0 + aoff + i * 2048 + cs0);
        b0[i] = *(const v4i*)(B0 + boff + i * 2048 + cs0);
    }

    const int NT = K_TOT / 64;           // 64 K-tiles
    for (int kt = 0; kt < NT; ++kt) {
        SFENCE();
        // 1) ds_read kk=1 of tile kt (consumed by step 7; hidden by step 3).
#pragma unroll
        for (int i = 0; i < 4; ++i) {
            a1[i] = *(const v4i*)(A0 + aoff + i * 2048 + cs1);
            b1[i] = *(const v4i*)(B0 + boff + i * 2048 + cs1);
        }
        SFENCE();
        // 2) Issue prefetch of tile kt+2 (fire-and-forget).
        if (kt + 2 < NT) {
            const long k0 = (long)(kt + 2) * 64;
#pragma unroll
            for (int i = 0; i < 4; ++i) {
                gload_lds16(pa + k0 + (long)i * 16 * K_TOT, A2 + lbase + i * 1024);
                gload_lds16(pb + k0 + (long)i * 16 * K_TOT, B2 + lbase + i * 1024);
            }
        }
        SFENCE();
        // 3) MFMA kk=0 (16): hides step-1 reads and step-2 issues.
#pragma unroll
        for (int i = 0; i < 4; ++i)
#pragma unroll
            for (int j = 0; j < 4; ++j)
                acc[i][j] = __builtin_amdgcn_mfma_i32_32x32x32_i8(
                    a0[i], b0[j], acc[i][j], 0, 0, 0);
        SFENCE();
        // 4-6) Publish/acquire + early read of tile kt+1's kk=0 fragments.
        if (kt + 1 < NT) {
            if (kt + 2 < NT) { WAIT_V8_L0(); } else { WAIT_V0_L0(); }
            SFENCE();
            SBAR();
            SFENCE();
#pragma unroll
            for (int i = 0; i < 4; ++i) {
                a0[i] = *(const v4i*)(A1 + aoff + i * 2048 + cs0);
                b0[i] = *(const v4i*)(B1 + boff + i * 2048 + cs0);
            }
            SFENCE();
        }
        // 7) MFMA kk=1 (16): hides step-6 reads (compiler lgkm-waits cover
        // the a1/b1 register deps from step 1, already drained by step 4).
#pragma unroll
        for (int i = 0; i < 4; ++i)
#pragma unroll
            for (int j = 0; j < 4; ++j)
                acc[i][j] = __builtin_amdgcn_mfma_i32_32x32x32_i8(
                    a1[i], b1[j], acc[i][j], 0, 0, 0);

        // Rotate buffers (register pointer swap, no dynamic indexing).
        signed char* t;
        t = A0; A0 = A1; A1 = A2; A2 = t;
        t = B0; B0 = B1; B1 = B2; B2 = t;
    }

    // Epilogue: C/D layout col=lane&31, row=(reg&3)+8*(reg>>2)+4*(lane>>5).
#pragma unroll
    for (int i = 0; i < 4; ++i) {
        const int mbase = bm0 + wr * 128 + i * 32 + 4 * kh;
#pragma unroll
        for (int j = 0; j < 4; ++j) {
            const int n = bn0 + wc * 128 + j * 32 + l31;
#pragma unroll
            for (int r = 0; r < 16; ++r) {
                const int m = mbase + (r & 3) + 8 * (r >> 2);
                out[(long)m * N_TOT + n] = acc[i][j][r];
            }
        }
    }
}

extern "C" void kernel_launch(void* const* d_in, const int* in_sizes, int n_in,
                              void* d_out, int out_size, void* d_ws, size_t ws_size,
                              hipStream_t stream) {
    const int* x32  = (const int*)d_in[0];  // [8192,4096] logical i8 as i32
    const int* w32  = (const int*)d_in[1];  // [4096,4096] logical i8 as i32
    const int* bias = (const int*)d_in[2];  // [4096] i32
    int*       out  = (int*)d_out;          // [8192,4096] i32

    signed char* xp = (signed char*)d_ws;
    signed char* wp = (signed char*)d_ws + (size_t)M_TOT * K_TOT;

    const int n4x = (M_TOT * K_TOT) / 4;  // 8388608 (divisible by 1024)
    const int n4w = (N_TOT * K_TOT) / 4;  // 4194304 (divisible by 1024)
    pack_i32_to_i8<<<n4x / 1024, 256, 0, stream>>>((const int4*)x32, (int*)xp, n4x);
    pack_i32_to_i8<<<n4w / 1024, 256, 0, stream>>>((const int4*)w32, (int*)wp, n4w);

    dim3 grid(N_TOT / 256, M_TOT / 256);  // (16, 32)
    i8gemm_bias<<<grid, 256, 0, stream>>>(xp, wp, bias, out);
}

// Round 4
// 399.792 us; speedup vs baseline: 1.0526x; 1.0095x over previous
//
#include <hip/hip_runtime.h>
#include <stdint.h>

// W8A8B32O32 Linear: y[m][n] = sum_k x[m][k]*w[n][k] + bias[n]
// M=8192, N=4096, K=4096. Inputs arrive as int32 (one int per logical int8
// element); pack to int8 in d_ws, then run the i8 MFMA GEMM.
#define M_TOT 8192
#define N_TOT 4096
#define K_TOT 4096

typedef int v4i  __attribute__((ext_vector_type(4)));
typedef int v16i __attribute__((ext_vector_type(16)));

__device__ __forceinline__ void gload_lds16(const void* g, void* l) {
    __builtin_amdgcn_global_load_lds(
        (const __attribute__((address_space(1))) unsigned int*)g,
        (__attribute__((address_space(3))) unsigned int*)l,
        16, 0, 0);
}

// gfx9 s_waitcnt simm16: vmcnt[3:0]@[3:0], expcnt@[6:4], lgkmcnt@[11:8],
// vmcnt[5:4]@[15:14].
#define WAIT_V2_L0() __builtin_amdgcn_s_waitcnt(0x0072)  // vmcnt(2) lgkmcnt(0)
#define WAIT_V0_L0() __builtin_amdgcn_s_waitcnt(0x0070)  // vmcnt(0) lgkmcnt(0)
#define WAIT_V4()    __builtin_amdgcn_s_waitcnt(0x0f74)  // vmcnt(4), lgkm free
#define SBAR()       __builtin_amdgcn_s_barrier()
#define SFENCE()     __builtin_amdgcn_sched_barrier(0)

// ---- fused pack int32 -> int8: 64B loads -> 16B store per thread-iter ----
// R3 post-mortem: the two 4B-store pack launches + overhead cost ~240 us for
// 240 MB of traffic (~40 us at roofline). One kernel, 16B stores, one launch.
// 524288 threads x 6 iters = 3145728 out-int4; iters 0-3 = x (2097152),
// iters 4-5 = w (1048576) -> the src/dst select is iteration-uniform.
__global__ __launch_bounds__(256) void pack2(
        const int4* __restrict__ xs, int4* __restrict__ xd,
        const int4* __restrict__ ws, int4* __restrict__ wd) {
    const int t = blockIdx.x * 256 + threadIdx.x;       // 0..524287
#pragma unroll
    for (int it = 0; it < 6; ++it) {
        const long g = (long)it * 524288 + t;
        const int4* __restrict__ src = (it < 4) ? xs : ws;
        int4* __restrict__ dst       = (it < 4) ? xd : wd;
        const long o = (it < 4) ? g : g - 2097152;
        int4 r;
        int* rp = (int*)&r;
#pragma unroll
        for (int q = 0; q < 4; ++q) {
            const int4 a = src[o * 4 + q];
            rp[q] = (a.x & 255) | ((a.y & 255) << 8) |
                    ((a.z & 255) << 16) | (a.w << 24);
        }
        dst[o] = r;
    }
}

// ---- GEMM: 512 threads = 8 waves (2/SIMD) computing a 256x256 tile -------
// R3 post-mortem: at 1 wave/SIMD (428 unified regs) the pipe idles 59% --
// every per-wave stall (lgkm drain before MFMA clusters, barrier skew) is
// SIMD-idle. R1 ruled out staging BW, R2 ruled out DMA latency depth. Fix:
// 8 waves, wave tile 128x64 -> acc = 8 v16i = 128 regs; launch_bounds(512,2)
// caps 256 unified regs/wave -> 2 waves/SIMD. Same proven skeleton: triple
// buffer, counted vmcnt, 2-phase kk split, 1 barrier/iter.
//
// Per K-iter (per wave; tile kt in A0/B0, kt+1 in A1/B1, kt+2 -> A2/B2):
//   1) ds_read kk=1 frags of kt (6)         (hidden under step 3)
//   2) issue 2 DMAs: A-half of kt+2
//   3) MFMA kk=0 x8 (setprio)
//   4) s_waitcnt vmcnt(2) lgkmcnt(0); s_barrier
//      [drains tile kt+1's 4 DMAs, keeps kt+2's 2 in flight; retires my reads]
//   5) ds_read kk=0 frags of kt+1 (6)       (hidden under step 7)
//   6) issue 2 DMAs: B-half of kt+2
//   7) MFMA kk=1 x8 (setprio)
//   rotate buffers.
// vmcnt ledger at step 4: outstanding = kt+1's 4 (issued last iter) + kt+2's
// 2 (step 2) = 6 -> vmcnt(2) == "kt+1 landed" (in-order decrement). Tail
// iters use vmcnt(0). Buffer-reuse proof: step-2/6 DMAs target the buffer of
// tile kt-1, whose last reads (iter kt-1 step 1) were retired by iter kt-1
// step 4's lgkmcnt(0) in EVERY wave before its barrier; our issue is after.
// Reads of kt+1 at step 5 are safe: each wave's own vmcnt drain of kt+1
// precedes the same barrier. Explicit waits are REQUIRED: compiler alias
// analysis does not connect global_load_lds's LDS write to the ds_reads.
// XOR chunk swizzle: stored_chunk = logical_chunk ^ ((row>>1)&3); staging
// stays linear-in-load-order (global_load_lds needs wave-uniform LDS base).
__global__ __launch_bounds__(512, 2) void i8gemm_bias(
        const signed char* __restrict__ x,
        const signed char* __restrict__ w,
        const int* __restrict__ bias,
        int* __restrict__ out) {
    __shared__ __align__(16) signed char la[3][256 * 64];
    __shared__ __align__(16) signed char lb[3][256 * 64];

    const int tid  = threadIdx.x;
    const int lane = tid & 63;           // 0..63
    const int wv   = tid >> 6;           // wave 0..7
    const int l31  = lane & 31;
    const int kh   = lane >> 5;          // K-half this lane supplies to MFMA
    const int wr   = wv >> 2;            // quadrant row (0..1) -> 128 rows
    const int wc   = wv & 3;             // quadrant col (0..3) -> 64 cols

    // XCD-aware bijective swizzle (512 blocks, 512%8==0): XCD k gets a
    // contiguous swz-range -> 4 A-panels x all 16 B-panels per XCD.
    const int flat = blockIdx.y * gridDim.x + blockIdx.x;   // 0..511
    const int swz  = (flat & 7) * 64 + (flat >> 3);
    const int bn0  = (swz & 15) * 256;
    const int bm0  = (swz >> 4) * 256;

    // Fused bias: C/D col = lane&31 -> bias is lane-constant per fragment.
    int bv[2];
#pragma unroll
    for (int j = 0; j < 2; ++j) bv[j] = bias[bn0 + wc * 64 + j * 32 + l31];
    v16i acc[4][2];
#pragma unroll
    for (int i = 0; i < 4; ++i)
#pragma unroll
        for (int j = 0; j < 2; ++j)
#pragma unroll
            for (int r = 0; r < 16; ++r) acc[i][j][r] = bv[j];

    // Staging: wave wv covers rows [wv*32, wv*32+32) of both A and B tiles:
    // 2 issues x (64 lanes x 16 B) each. Issue i covers rows i*16+(lane>>2);
    // stored chunk = lane&3; fetched chunk = (lane&3) ^ ((row>>1)&3)
    // = (lane&3) ^ ((lane>>3)&3)  (wv*32 and i*16 are 0 mod 8 after >>1: 0 mod 4).
    const int fc = (lane & 3) ^ ((lane >> 3) & 3);
    const signed char* pa = x + (long)(bm0 + wv * 32 + (lane >> 2)) * K_TOT + fc * 16;
    const signed char* pb = w + (long)(bn0 + wv * 32 + (lane >> 2)) * K_TOT + fc * 16;
    const int lbase = wv * 32 * 64;      // byte offset of this wave's rows

    // Fragment reads: A row = wr*128 + i*32 + l31, B row = wc*64 + j*32 + l31
    // -> swizzle = (l31>>1)&3 (bases are 0 mod 8). Logical chunk kk*2+kh is
    // stored at position (kk*2+kh)^swr.
    const int swr  = (l31 >> 1) & 3;
    const int aoff = (wr * 128 + l31) * 64;
    const int boff = (wc * 64  + l31) * 64;
    const int cs0  = ((kh    ) ^ swr) * 16;   // kk=0 chunk byte offset
    const int cs1  = ((2 + kh) ^ swr) * 16;   // kk=1 chunk byte offset

    // Rotating buffer pointers: A0/B0 = tile kt, A1/B1 = kt+1, A2/B2 = kt+2.
    signed char* A0 = &la[0][0]; signed char* A1 = &la[1][0]; signed char* A2 = &la[2][0];
    signed char* B0 = &lb[0][0]; signed char* B1 = &lb[1][0]; signed char* B2 = &lb[2][0];

    // Prologue: stage tile 0 then tile 1 (grouped per tile: vmcnt decrements
    // in issue order). 4 DMAs per tile per wave (2 A-rows + 2 B-rows).
#pragma unroll
    for (int i = 0; i < 2; ++i) {
        gload_lds16(pa + (long)i * 16 * K_TOT, A0 + lbase + i * 1024);
        gload_lds16(pb + (long)i * 16 * K_TOT, B0 + lbase + i * 1024);
    }
#pragma unroll
    for (int i = 0; i < 2; ++i) {
        gload_lds16(pa + 64 + (long)i * 16 * K_TOT, A1 + lbase + i * 1024);
        gload_lds16(pb + 64 + (long)i * 16 * K_TOT, B1 + lbase + i * 1024);
    }
    WAIT_V4();                 // tile 0 landed (tile 1's 4 stay in flight)
    SBAR();
    SFENCE();

    // Preload kk=0 fragments of tile 0.
    v4i a0[4], b0[2], a1[4], b1[2];
#pragma unroll
    for (int i = 0; i < 4; ++i) a0[i] = *(const v4i*)(A0 + aoff + i * 2048 + cs0);
#pragma unroll
    for (int j = 0; j < 2; ++j) b0[j] = *(const v4i*)(B0 + boff + j * 2048 + cs0);

    const int NT = K_TOT / 64;           // 64 K-tiles
    for (int kt = 0; kt < NT; ++kt) {
        SFENCE();
        // 1) ds_read kk=1 of tile kt (consumed by step 7; hidden by step 3).
#pragma unroll
        for (int i = 0; i < 4; ++i) a1[i] = *(const v4i*)(A0 + aoff + i * 2048 + cs1);
#pragma unroll
        for (int j = 0; j < 2; ++j) b1[j] = *(const v4i*)(B0 + boff + j * 2048 + cs1);
        SFENCE();
        // 2) Issue A-half prefetch of tile kt+2 (fire-and-forget).
        if (kt + 2 < NT) {
            const long k0 = (long)(kt + 2) * 64;
#pragma unroll
            for (int i = 0; i < 2; ++i)
                gload_lds16(pa + k0 + (long)i * 16 * K_TOT, A2 + lbase + i * 1024);
        }
        SFENCE();
        // 3) MFMA kk=0 (8): hides step-1 reads and step-2 issues.
        __builtin_amdgcn_s_setprio(1);
#pragma unroll
        for (int i = 0; i < 4; ++i)
#pragma unroll
            for (int j = 0; j < 2; ++j)
                acc[i][j] = __builtin_amdgcn_mfma_i32_32x32x32_i8(
                    a0[i], b0[j], acc[i][j], 0, 0, 0);
        __builtin_amdgcn_s_setprio(0);
        SFENCE();
        // 4) Publish/acquire: tile kt+1 landed everywhere, my reads retired.
        if (kt + 2 < NT) { WAIT_V2_L0(); } else { WAIT_V0_L0(); }
        SFENCE();
        SBAR();
        SFENCE();
        // 5) ds_read kk=0 of tile kt+1 (hidden by step 7).
        if (kt + 1 < NT) {
#pragma unroll
            for (int i = 0; i < 4; ++i) a0[i] = *(const v4i*)(A1 + aoff + i * 2048 + cs0);
#pragma unroll
            for (int j = 0; j < 2; ++j) b0[j] = *(const v4i*)(B1 + boff + j * 2048 + cs0);
        }
        SFENCE();
        // 6) Issue B-half prefetch of tile kt+2 (fire-and-forget).
        if (kt + 2 < NT) {
            const long k0 = (long)(kt + 2) * 64;
#pragma unroll
            for (int i = 0; i < 2; ++i)
                gload_lds16(pb + k0 + (long)i * 16 * K_TOT, B2 + lbase + i * 1024);
        }
        SFENCE();
        // 7) MFMA kk=1 (8): hides step-5 reads (a1/b1 drained at step 4).
        __builtin_amdgcn_s_setprio(1);
#pragma unroll
        for (int i = 0; i < 4; ++i)
#pragma unroll
            for (int j = 0; j < 2; ++j)
                acc[i][j] = __builtin_amdgcn_mfma_i32_32x32x32_i8(
                    a1[i], b1[j], acc[i][j], 0, 0, 0);

        // Rotate buffers (register pointer swap, no dynamic indexing).
        signed char* t;
        t = A0; A0 = A1; A1 = A2; A2 = t;
        t = B0; B0 = B1; B1 = B2; B2 = t;
    }

    // Epilogue: C/D layout col=lane&31, row=(reg&3)+8*(reg>>2)+4*(lane>>5).
#pragma unroll
    for (int i = 0; i < 4; ++i) {
        const int mbase = bm0 + wr * 128 + i * 32 + 4 * kh;
#pragma unroll
        for (int j = 0; j < 2; ++j) {
            const int n = bn0 + wc * 64 + j * 32 + l31;
#pragma unroll
            for (int r = 0; r < 16; ++r) {
                const int m = mbase + (r & 3) + 8 * (r >> 2);
                out[(long)m * N_TOT + n] = acc[i][j][r];
            }
        }
    }
}

extern "C" void kernel_launch(void* const* d_in, const int* in_sizes, int n_in,
                              void* d_out, int out_size, void* d_ws, size_t ws_size,
                              hipStream_t stream) {
    const int* x32  = (const int*)d_in[0];  // [8192,4096] logical i8 as i32
    const int* w32  = (const int*)d_in[1];  // [4096,4096] logical i8 as i32
    const int* bias = (const int*)d_in[2];  // [4096] i32
    int*       out  = (int*)d_out;          // [8192,4096] i32

    signed char* xp = (signed char*)d_ws;
    signed char* wp = (signed char*)d_ws + (size_t)M_TOT * K_TOT;

    pack2<<<2048, 256, 0, stream>>>((const int4*)x32, (int4*)xp,
                                    (const int4*)w32, (int4*)wp);

    dim3 grid(N_TOT / 256, M_TOT / 256);  // (16, 32)
    i8gemm_bias<<<grid, 512, 0, stream>>>(xp, wp, bias, out);
}